// Round 6
// baseline (370.152 us; speedup 1.0000x reference)
//
#include <hip/hip_runtime.h>
#include <hip/hip_bf16.h>

#define NPTS 131072
#define DIM  512
#define HID  128
#define KCL  3
#define NPOSI 8192
#define NNEGI 8192

typedef __attribute__((ext_vector_type(8))) short bf16x8;
typedef __attribute__((ext_vector_type(4))) float f32x4;

// ws layout (float offsets)
enum {
  WS_SHIFT_POS = 0,        // 512
  WS_SHIFT_NEG = 512,      // 512
  WS_NEGSUM    = 1024,     // 512
  WS_NEGPART   = 1536,     // 256*512 -> ends 132608
  WS_SUMS      = 132608,   // 4*1539 -> ends 138764
  WS_PPROTO    = 138764,   // 4*512 -> 140812
  WS_PN        = 140812,   // 4 -> 140816
  WS_W1FRAG    = 140816,   // 8192 frags * 4 floats = 32768 -> 173584
  WS_CLSL      = 173584,   // 131072 -> 304656 floats (~1.22 MB)
};
#define SUMS_STRIDE 1539

__device__ __forceinline__ short f2bf(float x) {
  __hip_bfloat16 h = __float2bfloat16(x);
  return *reinterpret_cast<short*>(&h);
}

// ================= k_prep: W1 frag-swizzle | calib | negmean partials | zero sums =================
__global__ __launch_bounds__(256, 1) void k_prep(const float* __restrict__ W1,
                                                 const float* __restrict__ Wp, const float* __restrict__ bp,
                                                 const float* __restrict__ Wn, const float* __restrict__ bn,
                                                 const float* __restrict__ pos_ctx, const float* __restrict__ neg_ctx,
                                                 const float* __restrict__ zp, const int* __restrict__ neg_idx,
                                                 float* __restrict__ ws) {
  int bid = blockIdx.x, t = threadIdx.x;
  if (bid < 32) {
    // pre-swizzled W1 MFMA fragments (bf16)
    int fid = bid * 256 + t;           // 0..8191
    int kc = fid >> 9;
    int n  = (fid >> 6) & 7;
    int l  = fid & 63;
    int row = n * 16 + (l & 15);
    int col = kc * 32 + (l >> 4) * 8;
    const float* src = W1 + (size_t)row * DIM + col;
    float4 v0 = *(const float4*)(src);
    float4 v1 = *(const float4*)(src + 4);
    bf16x8 f;
    f[0] = f2bf(v0.x); f[1] = f2bf(v0.y); f[2] = f2bf(v0.z); f[3] = f2bf(v0.w);
    f[4] = f2bf(v1.x); f[5] = f2bf(v1.y); f[6] = f2bf(v1.z); f[7] = f2bf(v1.w);
    ((bf16x8*)(ws + WS_W1FRAG))[fid] = f;
  } else if (bid < 64) {
    // calibration matvec: shift = 0.15*(W @ ctx + b)
    int b = bid - 32;
    int mat = b >> 4;
    const float* W    = mat ? Wn : Wp;
    const float* bias = mat ? bn : bp;
    const float* ctx  = mat ? neg_ctx : pos_ctx;
    float* outp = ws + (mat ? WS_SHIFT_NEG : WS_SHIFT_POS);
    int row = (b & 15) * 32 + (t >> 3);
    int sub = t & 7;
    const float* wr = W + row * DIM + sub * 64;
    const float* cr = ctx + sub * 64;
    float s = 0.f;
#pragma unroll
    for (int j = 0; j < 64; j += 4) {
      float4 w4 = *(const float4*)(wr + j);
      float4 c4 = *(const float4*)(cr + j);
      s += w4.x * c4.x + w4.y * c4.y + w4.z * c4.z + w4.w * c4.w;
    }
    s += __shfl_xor(s, 1);
    s += __shfl_xor(s, 2);
    s += __shfl_xor(s, 4);
    if (sub == 0) outp[row] = 0.15f * (s + bias[row]);
  } else if (bid < 320) {
    // neg gather-mean partials: 256 blocks x 32 rows, 8-deep pipelined gathers
    int jb = bid - 64;
    int c0 = t * 2;
    float a0 = 0.f, a1 = 0.f;
    int base = jb * 32;
#pragma unroll 8
    for (int jj = 0; jj < 32; ++jj) {
      int row = neg_idx[base + jj];
      float2 v = *(const float2*)(zp + (size_t)row * DIM + c0);
      a0 += v.x; a1 += v.y;
    }
    ws[WS_NEGPART + jb * DIM + c0]     = a0;
    ws[WS_NEGPART + jb * DIM + c0 + 1] = a1;
  } else {
    for (int idx = t; idx < 4 * SUMS_STRIDE; idx += 256) ws[WS_SUMS + idx] = 0.f;
  }
}

// ================= k_km<IT>: recompute center chain, assign, accumulate =================
template <int IT>
__global__ __launch_bounds__(256, 1) void k_km(const float* __restrict__ zp,
                                               const int* __restrict__ pos_idx,
                                               float* __restrict__ ws) {
  int bid = blockIdx.x, t = threadIdx.x;
  if (IT == 0 && bid == 512) {
    int c0 = t * 2;
    float a0 = 0.f, a1 = 0.f;
#pragma unroll 8
    for (int j = 0; j < 256; ++j) {
      float2 v = *(const float2*)(ws + WS_NEGPART + j * DIM + c0);
      a0 += v.x; a1 += v.y;
    }
    ws[WS_NEGSUM + c0]     = a0;
    ws[WS_NEGSUM + c0 + 1] = a1;
    return;
  }
  __shared__ float cc[KCL * DIM];
  __shared__ float cn[KCL];
  __shared__ float lsum[KCL * DIM];
  __shared__ float lcnt[KCL];
  int w = t >> 6, l = t & 63;

  for (int idx = t; idx < KCL * DIM; idx += 256) lsum[idx] = 0.f;
  if (t < KCL) lcnt[t] = 0.f;

  for (int idx = t; idx < KCL * DIM; idx += 256) {
    int k = idx >> 9;
    int sel = (k == 0) ? 0 : ((k == 1) ? 4095 : 8191);
    float v = zp[(size_t)pos_idx[sel] * DIM + (idx & 511)];
#pragma unroll
    for (int j = 0; j < IT; ++j) {
      float cntv = ws[WS_SUMS + j * SUMS_STRIDE + 3 * DIM + k];
      float sv   = ws[WS_SUMS + j * SUMS_STRIDE + idx];
      v = (cntv > 0.f) ? sv / cntv : v;
    }
    cc[idx] = v;
  }
  __syncthreads();
  if (w < KCL) {
    float s = 0.f;
#pragma unroll
    for (int m = 0; m < 8; ++m) { float v = cc[w * DIM + l + m * 64]; s += v * v; }
#pragma unroll
    for (int m = 1; m < 64; m <<= 1) s += __shfl_xor(s, m);
    if (l == 0) cn[w] = s;
  }
  __syncthreads();

  float ck0[8], ck1[8], ck2[8];
#pragma unroll
  for (int j = 0; j < 8; ++j) {
    ck0[j] = cc[0 * DIM + l * 8 + j];
    ck1[j] = cc[1 * DIM + l * 8 + j];
    ck2[j] = cc[2 * DIM + l * 8 + j];
  }
  float cn0 = cn[0], cn1 = cn[1], cn2 = cn[2];
  float acc0[8] = {0,0,0,0,0,0,0,0}, acc1[8] = {0,0,0,0,0,0,0,0}, acc2[8] = {0,0,0,0,0,0,0,0};
  float cnt0 = 0.f, cnt1 = 0.f, cnt2 = 0.f;

  int wid = bid * 4 + w;   // 2048 waves, 4 rows each, fully in flight
#pragma unroll 4
  for (int p = wid; p < NPOSI; p += 2048) {
    int row = pos_idx[p];
    const float* xr = zp + (size_t)row * DIM + l * 8;
    float4 x0 = *(const float4*)(xr);
    float4 x1 = *(const float4*)(xr + 4);
    float x[8] = {x0.x, x0.y, x0.z, x0.w, x1.x, x1.y, x1.z, x1.w};
    float d0 = 0.f, d1 = 0.f, d2 = 0.f;
#pragma unroll
    for (int j = 0; j < 8; ++j) { d0 += x[j] * ck0[j]; d1 += x[j] * ck1[j]; d2 += x[j] * ck2[j]; }
#pragma unroll
    for (int m = 1; m < 64; m <<= 1) {
      d0 += __shfl_xor(d0, m); d1 += __shfl_xor(d1, m); d2 += __shfl_xor(d2, m);
    }
    float t0 = cn0 - 2.f * d0, t1 = cn1 - 2.f * d1, t2 = cn2 - 2.f * d2;
    int a = 0; float best = t0;
    if (t1 < best) { best = t1; a = 1; }
    if (t2 < best) { best = t2; a = 2; }
    if (a == 0)      { cnt0 += 1.f;
#pragma unroll
      for (int j = 0; j < 8; ++j) acc0[j] += x[j]; }
    else if (a == 1) { cnt1 += 1.f;
#pragma unroll
      for (int j = 0; j < 8; ++j) acc1[j] += x[j]; }
    else             { cnt2 += 1.f;
#pragma unroll
      for (int j = 0; j < 8; ++j) acc2[j] += x[j]; }
  }
#pragma unroll
  for (int j = 0; j < 8; ++j) {
    atomicAdd(&lsum[0 * DIM + l * 8 + j], acc0[j]);
    atomicAdd(&lsum[1 * DIM + l * 8 + j], acc1[j]);
    atomicAdd(&lsum[2 * DIM + l * 8 + j], acc2[j]);
  }
  if (l == 0) {
    atomicAdd(&lcnt[0], cnt0); atomicAdd(&lcnt[1], cnt1); atomicAdd(&lcnt[2], cnt2);
  }
  __syncthreads();
  for (int idx = t; idx < KCL * DIM; idx += 256) atomicAdd(&ws[WS_SUMS + IT * SUMS_STRIDE + idx], lsum[idx]);
  if (t < KCL) atomicAdd(&ws[WS_SUMS + IT * SUMS_STRIDE + 3 * DIM + t], lcnt[t]);
}

// ================= k_fin: finalize prototypes + norms once =================
__global__ __launch_bounds__(256) void k_fin(const float* __restrict__ zp,
                                             const int* __restrict__ pos_idx,
                                             float* __restrict__ ws,
                                             float* __restrict__ out) {
  __shared__ __align__(16) float pp[4 * DIM];
  int t = threadIdx.x, w = t >> 6, l = t & 63;
  for (int idx = t; idx < KCL * DIM; idx += 256) {
    int k = idx >> 9, d = idx & 511;
    int sel = (k == 0) ? 0 : ((k == 1) ? 4095 : 8191);
    float v = zp[(size_t)pos_idx[sel] * DIM + d];
#pragma unroll
    for (int j = 0; j < 4; ++j) {
      float cntv = ws[WS_SUMS + j * SUMS_STRIDE + 3 * DIM + k];
      float sv   = ws[WS_SUMS + j * SUMS_STRIDE + idx];
      v = (cntv > 0.f) ? sv / cntv : v;
    }
    pp[idx] = v + ws[WS_SHIFT_POS + d];
  }
  for (int d = t; d < DIM; d += 256)
    pp[3 * DIM + d] = ws[WS_NEGSUM + d] * (1.f / NNEGI) + ws[WS_SHIFT_NEG + d];
  __syncthreads();
  {
    float s = 0.f;
#pragma unroll
    for (int m = 0; m < 8; ++m) { float v = pp[w * DIM + l + m * 64]; s += v * v; }
#pragma unroll
    for (int m = 1; m < 64; m <<= 1) s += __shfl_xor(s, m);
    if (l == 0) ws[WS_PN + w] = s;
  }
  for (int idx = t; idx < 4 * DIM; idx += 256) {
    ws[WS_PPROTO + idx] = pp[idx];
    out[7 * NPTS + idx] = pp[idx];
  }
}

// ================= k_cls: persistent, W1 fully LDS-resident, barrier-free MFMA loop =================
__global__ __launch_bounds__(256, 1) void k_cls(const float* __restrict__ zc,
                                                const float* __restrict__ b1,
                                                const float* __restrict__ W2,
                                                const float* __restrict__ b2,
                                                float* __restrict__ ws) {
  __shared__ bf16x8 Bs[8192];    // 128 KB: all of W1 as MFMA fragments
  int t = threadIdx.x, w = t >> 6, l = t & 63;
  const bf16x8* w1f = (const bf16x8*)(ws + WS_W1FRAG);
#pragma unroll 4
  for (int idx = t; idx < 8192; idx += 256) Bs[idx] = w1f[idx];

  int col_l = l & 15;
  float b1c[8], w2c[8];
#pragma unroll
  for (int n = 0; n < 8; ++n) { b1c[n] = b1[n * 16 + col_l]; w2c[n] = W2[n * 16 + col_l]; }
  float b2v = b2[0];
  __syncthreads();

  for (int tile = 0; tile < 8; ++tile) {
    int i0 = (blockIdx.x * 8 + tile) * 64;
    const float* aptr = zc + (size_t)(i0 + w * 16 + (l & 15)) * DIM + (l >> 4) * 8;

    f32x4 acc[8];
#pragma unroll
    for (int n = 0; n < 8; ++n) acc[n] = (f32x4){0.f, 0.f, 0.f, 0.f};

    float4 A[8][2];
#pragma unroll
    for (int s = 0; s < 8; ++s) {
      A[s][0] = *(const float4*)(aptr + s * 32);
      A[s][1] = *(const float4*)(aptr + s * 32 + 4);
    }
#pragma unroll
    for (int kc = 0; kc < 16; ++kc) {
      float4 a0 = A[kc & 7][0], a1 = A[kc & 7][1];
      if (kc < 8) {
        A[kc][0] = *(const float4*)(aptr + (kc + 8) * 32);
        A[kc][1] = *(const float4*)(aptr + (kc + 8) * 32 + 4);
      }
      bf16x8 af;
      af[0] = f2bf(a0.x); af[1] = f2bf(a0.y); af[2] = f2bf(a0.z); af[3] = f2bf(a0.w);
      af[4] = f2bf(a1.x); af[5] = f2bf(a1.y); af[6] = f2bf(a1.z); af[7] = f2bf(a1.w);
#pragma unroll
      for (int n = 0; n < 8; ++n)
        acc[n] = __builtin_amdgcn_mfma_f32_16x16x32_bf16(af, Bs[kc * 512 + n * 64 + l], acc[n], 0, 0, 0);
    }
    // epilogue: relu + W2 dot -> cls_logit
    float p[4] = {0.f, 0.f, 0.f, 0.f};
#pragma unroll
    for (int n = 0; n < 8; ++n) {
#pragma unroll
      for (int r = 0; r < 4; ++r) {
        float h = acc[n][r] + b1c[n];
        h = h > 0.f ? h : 0.f;
        p[r] += h * w2c[n];
      }
    }
#pragma unroll
    for (int m = 1; m < 16; m <<= 1) {
#pragma unroll
      for (int r = 0; r < 4; ++r) p[r] += __shfl_xor(p[r], m);
    }
    if (col_l == 0) {
      int rbase = i0 + w * 16 + (l >> 4) * 4;
#pragma unroll
      for (int r = 0; r < 4; ++r) ws[WS_CLSL + rbase + r] = p[r] + b2v;
    }
  }
}

// ================= k_proto: streaming VALU distances + fused epilogue =================
__global__ __launch_bounds__(256, 2) void k_proto(const float* __restrict__ zp,
                                                  const float* __restrict__ ws,
                                                  float* __restrict__ out) {
  __shared__ __align__(16) float pp[4 * DIM];
  __shared__ float pns[4];
  int t = threadIdx.x;
  for (int idx = t; idx < 4 * DIM; idx += 256) pp[idx] = ws[WS_PPROTO + idx];
  if (t < 4) pns[t] = ws[WS_PN + t];
  __syncthreads();

  int w = t >> 6, l = t & 63, s = l & 7, r = l >> 3;
  int i = blockIdx.x * 32 + w * 8 + r;
  const float* xr = zp + (size_t)i * DIM;

  float4 x[16];
#pragma unroll
  for (int j = 0; j < 16; ++j) x[j] = *(const float4*)(xr + j * 32 + s * 4);

  float d0 = 0.f, d1 = 0.f, d2 = 0.f, dn = 0.f, sx = 0.f;
#pragma unroll
  for (int j = 0; j < 16; ++j) {
    int col = j * 32 + s * 4;
    float4 c0 = *(const float4*)(&pp[0 * DIM + col]);
    float4 c1 = *(const float4*)(&pp[1 * DIM + col]);
    float4 c2 = *(const float4*)(&pp[2 * DIM + col]);
    float4 c3 = *(const float4*)(&pp[3 * DIM + col]);
    d0 += x[j].x * c0.x + x[j].y * c0.y + x[j].z * c0.z + x[j].w * c0.w;
    d1 += x[j].x * c1.x + x[j].y * c1.y + x[j].z * c1.z + x[j].w * c1.w;
    d2 += x[j].x * c2.x + x[j].y * c2.y + x[j].z * c2.z + x[j].w * c2.w;
    dn += x[j].x * c3.x + x[j].y * c3.y + x[j].z * c3.z + x[j].w * c3.w;
    sx += x[j].x * x[j].x + x[j].y * x[j].y + x[j].z * x[j].z + x[j].w * x[j].w;
  }
#pragma unroll
  for (int m = 1; m < 8; m <<= 1) {
    d0 += __shfl_xor(d0, m);
    d1 += __shfl_xor(d1, m);
    d2 += __shfl_xor(d2, m);
    dn += __shfl_xor(dn, m);
    sx += __shfl_xor(sx, m);
  }
  if (s == 0) {
    float e0 = sx + pns[0] - 2.f * d0; e0 = fmaxf(e0, 0.f);
    float e1 = sx + pns[1] - 2.f * d1; e1 = fmaxf(e1, 0.f);
    float e2 = sx + pns[2] - 2.f * d2; e2 = fmaxf(e2, 0.f);
    float dpos = e0; int a = 0;
    if (e1 < dpos) { dpos = e1; a = 1; }
    if (e2 < dpos) { dpos = e2; a = 2; }
    float dneg = (sx + pns[3] - 2.f * dn) * (1.f / DIM);
    float plog = (dneg - dpos) * 0.04419417382415922f;   // 1/sqrt(512)
    float o2 = 0.2f * plog;
    float lg = (ws[WS_CLSL + i] + o2) * 0.4f;            // /2.5
    float prob = 1.f / (1.f + expf(-lg));
    out[i]            = lg;
    out[NPTS + i]     = prob;
    out[2 * NPTS + i] = o2;
    out[3 * NPTS + i] = (float)a;
    out[4 * NPTS + 3 * i]     = e0;
    out[4 * NPTS + 3 * i + 1] = e1;
    out[4 * NPTS + 3 * i + 2] = e2;
  }
}

extern "C" void kernel_launch(void* const* d_in, const int* in_sizes, int n_in,
                              void* d_out, int out_size, void* d_ws, size_t ws_size,
                              hipStream_t stream) {
  const float* z_cls   = (const float*)d_in[0];
  const float* z_proto = (const float*)d_in[1];
  const float* pos_ctx = (const float*)d_in[2];
  const float* neg_ctx = (const float*)d_in[3];
  const float* W1      = (const float*)d_in[4];
  const float* b1      = (const float*)d_in[5];
  const float* W2      = (const float*)d_in[6];
  const float* b2      = (const float*)d_in[7];
  const float* Wp      = (const float*)d_in[8];
  const float* bp      = (const float*)d_in[9];
  const float* Wn      = (const float*)d_in[10];
  const float* bn      = (const float*)d_in[11];
  const int* pos_idx   = (const int*)d_in[12];
  const int* neg_idx   = (const int*)d_in[13];
  float* out           = (float*)d_out;
  float* ws            = (float*)d_ws;

  k_prep<<<321, 256, 0, stream>>>(W1, Wp, bp, Wn, bn, pos_ctx, neg_ctx, z_proto, neg_idx, ws);
  k_cls<<<256, 256, 0, stream>>>(z_cls, b1, W2, b2, ws);
  k_km<0><<<513, 256, 0, stream>>>(z_proto, pos_idx, ws);
  k_km<1><<<512, 256, 0, stream>>>(z_proto, pos_idx, ws);
  k_km<2><<<512, 256, 0, stream>>>(z_proto, pos_idx, ws);
  k_km<3><<<512, 256, 0, stream>>>(z_proto, pos_idx, ws);
  k_fin<<<1, 256, 0, stream>>>(z_proto, pos_idx, ws, out);
  k_proto<<<NPTS / 32, 256, 0, stream>>>(z_proto, ws, out);
}

// Round 7
// 293.659 us; speedup vs baseline: 1.2605x; 1.2605x over previous
//
#include <hip/hip_runtime.h>
#include <hip/hip_bf16.h>

#define NPTS 131072
#define DIM  512
#define HID  128
#define KCL  3
#define NPOSI 8192
#define NNEGI 8192

typedef __attribute__((ext_vector_type(8))) short bf16x8;
typedef __attribute__((ext_vector_type(4))) float f32x4;

// ws layout (float offsets)
enum {
  WS_SHIFT_POS = 0,        // 512
  WS_SHIFT_NEG = 512,      // 512
  WS_NEGSUM    = 1024,     // 512
  WS_NEGPART   = 1536,     // 256*512 -> ends 132608
  WS_SUMS      = 132608,   // 4*1539 -> ends 138764
  WS_PPROTO    = 138764,   // 4*512 -> 140812
  WS_PN        = 140812,   // 4 -> 140816
  WS_W1FRAG    = 140816,   // 32768 -> 173584
  WS_CLSL      = 173584,   // 131072 -> 304656
  WS_POSG      = 304656,   // dense gather of z_proto[pos_idx]: 8192*512 -> 4498960 (~18MB)
};
#define SUMS_STRIDE 1539

__device__ __forceinline__ short f2bf(float x) {
  __hip_bfloat16 h = __float2bfloat16(x);
  return *reinterpret_cast<short*>(&h);
}

// ================= k_prep: W1 frag-swizzle | calib | negmean partials | pos gather | zero sums =================
__global__ __launch_bounds__(256) void k_prep(const float* __restrict__ W1,
                                              const float* __restrict__ Wp, const float* __restrict__ bp,
                                              const float* __restrict__ Wn, const float* __restrict__ bn,
                                              const float* __restrict__ pos_ctx, const float* __restrict__ neg_ctx,
                                              const float* __restrict__ zp,
                                              const int* __restrict__ neg_idx, const int* __restrict__ pos_idx,
                                              float* __restrict__ ws) {
  int bid = blockIdx.x, t = threadIdx.x;
  if (bid < 32) {
    // pre-swizzled W1 MFMA fragments (bf16)
    int fid = bid * 256 + t;           // 0..8191
    int kc = fid >> 9;
    int n  = (fid >> 6) & 7;
    int l  = fid & 63;
    int row = n * 16 + (l & 15);
    int col = kc * 32 + (l >> 4) * 8;
    const float* src = W1 + (size_t)row * DIM + col;
    float4 v0 = *(const float4*)(src);
    float4 v1 = *(const float4*)(src + 4);
    bf16x8 f;
    f[0] = f2bf(v0.x); f[1] = f2bf(v0.y); f[2] = f2bf(v0.z); f[3] = f2bf(v0.w);
    f[4] = f2bf(v1.x); f[5] = f2bf(v1.y); f[6] = f2bf(v1.z); f[7] = f2bf(v1.w);
    ((bf16x8*)(ws + WS_W1FRAG))[fid] = f;
  } else if (bid < 64) {
    // calibration matvec: shift = 0.15*(W @ ctx + b)
    int b = bid - 32;
    int mat = b >> 4;
    const float* W    = mat ? Wn : Wp;
    const float* bias = mat ? bn : bp;
    const float* ctx  = mat ? neg_ctx : pos_ctx;
    float* outp = ws + (mat ? WS_SHIFT_NEG : WS_SHIFT_POS);
    int row = (b & 15) * 32 + (t >> 3);
    int sub = t & 7;
    const float* wr = W + row * DIM + sub * 64;
    const float* cr = ctx + sub * 64;
    float s = 0.f;
#pragma unroll
    for (int j = 0; j < 64; j += 4) {
      float4 w4 = *(const float4*)(wr + j);
      float4 c4 = *(const float4*)(cr + j);
      s += w4.x * c4.x + w4.y * c4.y + w4.z * c4.z + w4.w * c4.w;
    }
    s += __shfl_xor(s, 1);
    s += __shfl_xor(s, 2);
    s += __shfl_xor(s, 4);
    if (sub == 0) outp[row] = 0.15f * (s + bias[row]);
  } else if (bid < 320) {
    // neg gather-mean partials: 256 blocks x 32 rows
    int jb = bid - 64;
    int c0 = t * 2;
    float a0 = 0.f, a1 = 0.f;
    int base = jb * 32;
#pragma unroll 8
    for (int jj = 0; jj < 32; ++jj) {
      int row = neg_idx[base + jj];
      float2 v = *(const float2*)(zp + (size_t)row * DIM + c0);
      a0 += v.x; a1 += v.y;
    }
    ws[WS_NEGPART + jb * DIM + c0]     = a0;
    ws[WS_NEGPART + jb * DIM + c0 + 1] = a1;
  } else if (bid < 448) {
    // dense gather: POSG[p] = zp[pos_idx[p]]  (128 blocks x 64 rows)
    int j = bid - 320;
    int w = t >> 6, l = t & 63;
    int row0 = j * 64 + w * 16;
#pragma unroll
    for (int rb = 0; rb < 16; rb += 4) {
      float4 a[4], b[4];
#pragma unroll
      for (int r = 0; r < 4; ++r) {
        const float* src = zp + (size_t)pos_idx[row0 + rb + r] * DIM + l * 8;
        a[r] = *(const float4*)(src);
        b[r] = *(const float4*)(src + 4);
      }
#pragma unroll
      for (int r = 0; r < 4; ++r) {
        float* dst = ws + WS_POSG + (size_t)(row0 + rb + r) * DIM + l * 8;
        *(float4*)(dst)     = a[r];
        *(float4*)(dst + 4) = b[r];
      }
    }
  } else {
    for (int idx = t; idx < 4 * SUMS_STRIDE; idx += 256) ws[WS_SUMS + idx] = 0.f;
  }
}

// ================= k_km<IT>: dense rows, recompute center chain, assign, accumulate =================
template <int IT>
__global__ __launch_bounds__(256, 1) void k_km(float* __restrict__ ws) {
  int bid = blockIdx.x, t = threadIdx.x;
  if (IT == 0 && bid == 512) {
    int c0 = t * 2;
    float a0 = 0.f, a1 = 0.f;
#pragma unroll 8
    for (int j = 0; j < 256; ++j) {
      float2 v = *(const float2*)(ws + WS_NEGPART + j * DIM + c0);
      a0 += v.x; a1 += v.y;
    }
    ws[WS_NEGSUM + c0]     = a0;
    ws[WS_NEGSUM + c0 + 1] = a1;
    return;
  }
  __shared__ float cc[KCL * DIM];
  __shared__ float cn[KCL];
  __shared__ float lsum[KCL * DIM];
  __shared__ float lcnt[KCL];
  int w = t >> 6, l = t & 63;

  for (int idx = t; idx < KCL * DIM; idx += 256) lsum[idx] = 0.f;
  if (t < KCL) lcnt[t] = 0.f;

  for (int idx = t; idx < KCL * DIM; idx += 256) {
    int k = idx >> 9;
    int sel = (k == 0) ? 0 : ((k == 1) ? 4095 : 8191);
    float v = ws[WS_POSG + (size_t)sel * DIM + (idx & 511)];
#pragma unroll
    for (int j = 0; j < IT; ++j) {
      float cntv = ws[WS_SUMS + j * SUMS_STRIDE + 3 * DIM + k];
      float sv   = ws[WS_SUMS + j * SUMS_STRIDE + idx];
      v = (cntv > 0.f) ? sv / cntv : v;
    }
    cc[idx] = v;
  }
  __syncthreads();
  if (w < KCL) {
    float s = 0.f;
#pragma unroll
    for (int m = 0; m < 8; ++m) { float v = cc[w * DIM + l + m * 64]; s += v * v; }
#pragma unroll
    for (int m = 1; m < 64; m <<= 1) s += __shfl_xor(s, m);
    if (l == 0) cn[w] = s;
  }
  __syncthreads();

  float ck0[8], ck1[8], ck2[8];
#pragma unroll
  for (int j = 0; j < 8; ++j) {
    ck0[j] = cc[0 * DIM + l * 8 + j];
    ck1[j] = cc[1 * DIM + l * 8 + j];
    ck2[j] = cc[2 * DIM + l * 8 + j];
  }
  float cn0 = cn[0], cn1 = cn[1], cn2 = cn[2];
  float acc0[8] = {0,0,0,0,0,0,0,0}, acc1[8] = {0,0,0,0,0,0,0,0}, acc2[8] = {0,0,0,0,0,0,0,0};
  float cnt0 = 0.f, cnt1 = 0.f, cnt2 = 0.f;

  // wave owns 4 CONSECUTIVE dense rows: contiguous 8KB stream per wave
  int p0 = (bid * 4 + w) * 4;
  const float* xbase = ws + WS_POSG + (size_t)p0 * DIM + l * 8;
  float4 xa[4], xb[4];
#pragma unroll
  for (int r = 0; r < 4; ++r) {
    xa[r] = *(const float4*)(xbase + r * DIM);
    xb[r] = *(const float4*)(xbase + r * DIM + 4);
  }
#pragma unroll
  for (int r = 0; r < 4; ++r) {
    float x[8] = {xa[r].x, xa[r].y, xa[r].z, xa[r].w, xb[r].x, xb[r].y, xb[r].z, xb[r].w};
    float d0 = 0.f, d1 = 0.f, d2 = 0.f;
#pragma unroll
    for (int j = 0; j < 8; ++j) { d0 += x[j] * ck0[j]; d1 += x[j] * ck1[j]; d2 += x[j] * ck2[j]; }
#pragma unroll
    for (int m = 1; m < 64; m <<= 1) {
      d0 += __shfl_xor(d0, m); d1 += __shfl_xor(d1, m); d2 += __shfl_xor(d2, m);
    }
    float t0 = cn0 - 2.f * d0, t1 = cn1 - 2.f * d1, t2 = cn2 - 2.f * d2;
    int a = 0; float best = t0;
    if (t1 < best) { best = t1; a = 1; }
    if (t2 < best) { best = t2; a = 2; }
    if (a == 0)      { cnt0 += 1.f;
#pragma unroll
      for (int j = 0; j < 8; ++j) acc0[j] += x[j]; }
    else if (a == 1) { cnt1 += 1.f;
#pragma unroll
      for (int j = 0; j < 8; ++j) acc1[j] += x[j]; }
    else             { cnt2 += 1.f;
#pragma unroll
      for (int j = 0; j < 8; ++j) acc2[j] += x[j]; }
  }
#pragma unroll
  for (int j = 0; j < 8; ++j) {
    atomicAdd(&lsum[0 * DIM + l * 8 + j], acc0[j]);
    atomicAdd(&lsum[1 * DIM + l * 8 + j], acc1[j]);
    atomicAdd(&lsum[2 * DIM + l * 8 + j], acc2[j]);
  }
  if (l == 0) {
    atomicAdd(&lcnt[0], cnt0); atomicAdd(&lcnt[1], cnt1); atomicAdd(&lcnt[2], cnt2);
  }
  __syncthreads();
  for (int idx = t; idx < KCL * DIM; idx += 256) atomicAdd(&ws[WS_SUMS + IT * SUMS_STRIDE + idx], lsum[idx]);
  if (t < KCL) atomicAdd(&ws[WS_SUMS + IT * SUMS_STRIDE + 3 * DIM + t], lcnt[t]);
}

// ================= k_fin: finalize prototypes + norms once =================
__global__ __launch_bounds__(256) void k_fin(float* __restrict__ ws, float* __restrict__ out) {
  __shared__ __align__(16) float pp[4 * DIM];
  int t = threadIdx.x, w = t >> 6, l = t & 63;
  for (int idx = t; idx < KCL * DIM; idx += 256) {
    int k = idx >> 9, d = idx & 511;
    int sel = (k == 0) ? 0 : ((k == 1) ? 4095 : 8191);
    float v = ws[WS_POSG + (size_t)sel * DIM + d];
#pragma unroll
    for (int j = 0; j < 4; ++j) {
      float cntv = ws[WS_SUMS + j * SUMS_STRIDE + 3 * DIM + k];
      float sv   = ws[WS_SUMS + j * SUMS_STRIDE + idx];
      v = (cntv > 0.f) ? sv / cntv : v;
    }
    pp[idx] = v + ws[WS_SHIFT_POS + d];
  }
  for (int d = t; d < DIM; d += 256)
    pp[3 * DIM + d] = ws[WS_NEGSUM + d] * (1.f / NNEGI) + ws[WS_SHIFT_NEG + d];
  __syncthreads();
  {
    float s = 0.f;
#pragma unroll
    for (int m = 0; m < 8; ++m) { float v = pp[w * DIM + l + m * 64]; s += v * v; }
#pragma unroll
    for (int m = 1; m < 64; m <<= 1) s += __shfl_xor(s, m);
    if (l == 0) ws[WS_PN + w] = s;
  }
  for (int idx = t; idx < 4 * DIM; idx += 256) {
    ws[WS_PPROTO + idx] = pp[idx];
    out[7 * NPTS + idx] = pp[idx];
  }
}

// ================= k_cls: wave-contiguous A stream -> wave-private LDS transpose -> barrier-free MFMA =================
__global__ __launch_bounds__(256) void k_cls(const float* __restrict__ zc,
                                             const float* __restrict__ b1,
                                             const float* __restrict__ W2,
                                             const float* __restrict__ b2,
                                             float* __restrict__ ws) {
  __shared__ bf16x8 Abuf[4096];   // 64KB: 4 waves x 16 rows x 512 cols (bf16), fragment-ordered
  int t = threadIdx.x, w = t >> 6, l = t & 63;
  int bid = (blockIdx.x & 7) * 256 + (blockIdx.x >> 3);   // bijective XCD swizzle (2048 % 8 == 0)
  int i0 = bid * 64;
  const bf16x8* w1f = (const bf16x8*)(ws + WS_W1FRAG);
  bf16x8* ab = Abuf + w * 1024;
  const float* arow = zc + (size_t)(i0 + w * 16) * DIM + l * 8;

  // ---- stage: 16 consecutive rows, contiguous 2KB per instruction-pair ----
#pragma unroll
  for (int Rb = 0; Rb < 16; Rb += 8) {
    float4 La[8], Lb[8];
#pragma unroll
    for (int r = 0; r < 8; ++r) {
      La[r] = *(const float4*)(arow + (size_t)(Rb + r) * DIM);
      Lb[r] = *(const float4*)(arow + (size_t)(Rb + r) * DIM + 4);
    }
#pragma unroll
    for (int r = 0; r < 8; ++r) {
      int R = Rb + r;
      bf16x8 ch;
      ch[0] = f2bf(La[r].x); ch[1] = f2bf(La[r].y); ch[2] = f2bf(La[r].z); ch[3] = f2bf(La[r].w);
      ch[4] = f2bf(Lb[r].x); ch[5] = f2bf(Lb[r].y); ch[6] = f2bf(Lb[r].z); ch[7] = f2bf(Lb[r].w);
      // lane l holds row R cols [l*8, l*8+8) -> frag kc=l>>2, dest lane = R + ((l&3)<<4)
      ab[(l >> 2) * 64 + R + ((l & 3) << 4)] = ch;
    }
  }

  // ---- compute: conflict-free A ds_reads + 1-deep B prefetch from L2 ----
  f32x4 acc[8];
#pragma unroll
  for (int n = 0; n < 8; ++n) acc[n] = (f32x4){0.f, 0.f, 0.f, 0.f};
  bf16x8 B[2][8];
#pragma unroll
  for (int n = 0; n < 8; ++n) B[0][n] = w1f[n * 64 + l];

#pragma unroll
  for (int kc = 0; kc < 16; ++kc) {
    bf16x8 af = ab[kc * 64 + l];
    if (kc + 1 < 16) {
#pragma unroll
      for (int n = 0; n < 8; ++n) B[(kc + 1) & 1][n] = w1f[(kc + 1) * 512 + n * 64 + l];
    }
#pragma unroll
    for (int n = 0; n < 8; ++n)
      acc[n] = __builtin_amdgcn_mfma_f32_16x16x32_bf16(af, B[kc & 1][n], acc[n], 0, 0, 0);
  }

  // ---- epilogue: relu + W2 dot -> cls_logit ----
  float p[4] = {0.f, 0.f, 0.f, 0.f};
  int col_l = l & 15;
#pragma unroll
  for (int n = 0; n < 8; ++n) {
    int col = n * 16 + col_l;
    float bb = b1[col], w2v = W2[col];
#pragma unroll
    for (int r = 0; r < 4; ++r) {
      float h = acc[n][r] + bb;
      h = h > 0.f ? h : 0.f;
      p[r] += h * w2v;
    }
  }
#pragma unroll
  for (int m = 1; m < 16; m <<= 1) {
#pragma unroll
    for (int r = 0; r < 4; ++r) p[r] += __shfl_xor(p[r], m);
  }
  if (col_l == 0) {
    float b2v = b2[0];
    int rbase = i0 + w * 16 + (l >> 4) * 4;
#pragma unroll
    for (int r = 0; r < 4; ++r) ws[WS_CLSL + rbase + r] = p[r] + b2v;
  }
}

// ================= k_proto: wave-contiguous 8-row stream + butterfly reduce + fused epilogue =================
__global__ __launch_bounds__(256) void k_proto(const float* __restrict__ zp,
                                               const float* __restrict__ ws,
                                               float* __restrict__ out) {
  __shared__ __align__(16) float pp[4 * DIM];
  __shared__ float pns[4];
  int t = threadIdx.x;
  for (int idx = t; idx < 4 * DIM; idx += 256) pp[idx] = ws[WS_PPROTO + idx];
  if (t < 4) pns[t] = ws[WS_PN + t];
  __syncthreads();

  int w = t >> 6, l = t & 63;
  int bid = (blockIdx.x & 7) * 512 + (blockIdx.x >> 3);   // bijective XCD swizzle (4096 % 8 == 0)
  int r0 = (bid * 4 + w) * 8;                             // 8 consecutive rows per wave
  const float* base = zp + (size_t)r0 * DIM + l * 8;

  float c0v[8], c1v[8], c2v[8], c3v[8];
#pragma unroll
  for (int j = 0; j < 8; ++j) {
    c0v[j] = pp[0 * DIM + l * 8 + j];
    c1v[j] = pp[1 * DIM + l * 8 + j];
    c2v[j] = pp[2 * DIM + l * 8 + j];
    c3v[j] = pp[3 * DIM + l * 8 + j];
  }
  float pn0 = pns[0], pn1 = pns[1], pn2 = pns[2], nn = pns[3];

  // load all 8 rows (16KB contiguous per wave) up front
  float4 xa[8], xb[8];
#pragma unroll
  for (int rr = 0; rr < 8; ++rr) {
    xa[rr] = *(const float4*)(base + rr * DIM);
    xb[rr] = *(const float4*)(base + rr * DIM + 4);
  }

  float r_lg = 0.f, r_pr = 0.f, r_o2 = 0.f, r_as = 0.f, r_e0 = 0.f, r_e1 = 0.f, r_e2 = 0.f;
#pragma unroll
  for (int rr = 0; rr < 8; ++rr) {
    float x[8] = {xa[rr].x, xa[rr].y, xa[rr].z, xa[rr].w, xb[rr].x, xb[rr].y, xb[rr].z, xb[rr].w};
    float d0 = 0.f, d1 = 0.f, d2 = 0.f, dn = 0.f, sx = 0.f;
#pragma unroll
    for (int j = 0; j < 8; ++j) {
      d0 += x[j] * c0v[j];
      d1 += x[j] * c1v[j];
      d2 += x[j] * c2v[j];
      dn += x[j] * c3v[j];
      sx += x[j] * x[j];
    }
#pragma unroll
    for (int m = 1; m < 64; m <<= 1) {
      d0 += __shfl_xor(d0, m);
      d1 += __shfl_xor(d1, m);
      d2 += __shfl_xor(d2, m);
      dn += __shfl_xor(dn, m);
      sx += __shfl_xor(sx, m);
    }
    float e0 = sx + pn0 - 2.f * d0; e0 = fmaxf(e0, 0.f);
    float e1 = sx + pn1 - 2.f * d1; e1 = fmaxf(e1, 0.f);
    float e2 = sx + pn2 - 2.f * d2; e2 = fmaxf(e2, 0.f);
    float dpos = e0; int a = 0;
    if (e1 < dpos) { dpos = e1; a = 1; }
    if (e2 < dpos) { dpos = e2; a = 2; }
    float dneg = (sx + nn - 2.f * dn) * (1.f / DIM);
    float plog = (dneg - dpos) * 0.04419417382415922f;   // 1/sqrt(512)
    float o2 = 0.2f * plog;
    float lg = (ws[WS_CLSL + r0 + rr] + o2) * 0.4f;      // /2.5
    float prob = 1.f / (1.f + expf(-lg));
    bool sel = (l == rr);
    r_lg = sel ? lg : r_lg;
    r_pr = sel ? prob : r_pr;
    r_o2 = sel ? o2 : r_o2;
    r_as = sel ? (float)a : r_as;
    r_e0 = sel ? e0 : r_e0;
    r_e1 = sel ? e1 : r_e1;
    r_e2 = sel ? e2 : r_e2;
  }
  if (l < 8) {
    int i = r0 + l;
    out[i]            = r_lg;
    out[NPTS + i]     = r_pr;
    out[2 * NPTS + i] = r_o2;
    out[3 * NPTS + i] = r_as;
    out[4 * NPTS + 3 * i]     = r_e0;
    out[4 * NPTS + 3 * i + 1] = r_e1;
    out[4 * NPTS + 3 * i + 2] = r_e2;
  }
}

extern "C" void kernel_launch(void* const* d_in, const int* in_sizes, int n_in,
                              void* d_out, int out_size, void* d_ws, size_t ws_size,
                              hipStream_t stream) {
  const float* z_cls   = (const float*)d_in[0];
  const float* z_proto = (const float*)d_in[1];
  const float* pos_ctx = (const float*)d_in[2];
  const float* neg_ctx = (const float*)d_in[3];
  const float* W1      = (const float*)d_in[4];
  const float* b1      = (const float*)d_in[5];
  const float* W2      = (const float*)d_in[6];
  const float* b2      = (const float*)d_in[7];
  const float* Wp      = (const float*)d_in[8];
  const float* bp      = (const float*)d_in[9];
  const float* Wn      = (const float*)d_in[10];
  const float* bn      = (const float*)d_in[11];
  const int* pos_idx   = (const int*)d_in[12];
  const int* neg_idx   = (const int*)d_in[13];
  float* out           = (float*)d_out;
  float* ws            = (float*)d_ws;

  k_prep<<<449, 256, 0, stream>>>(W1, Wp, bp, Wn, bn, pos_ctx, neg_ctx, z_proto, neg_idx, pos_idx, ws);
  k_cls<<<NPTS / 64, 256, 0, stream>>>(z_cls, b1, W2, b2, ws);
  k_km<0><<<513, 256, 0, stream>>>(ws);
  k_km<1><<<512, 256, 0, stream>>>(ws);
  k_km<2><<<512, 256, 0, stream>>>(ws);
  k_km<3><<<512, 256, 0, stream>>>(ws);
  k_fin<<<1, 256, 0, stream>>>(ws, out);
  k_proto<<<NPTS / 32, 256, 0, stream>>>(z_proto, ws, out);
}